// Round 15
// baseline (299.190 us; speedup 1.0000x reference)
//
#include <hip/hip_runtime.h>
#include <hip/hip_bf16.h>

#define N_NODES 40000
#define N_EDGES 640000
#define E_TOT   (N_EDGES + N_NODES)
#define NUM_GRAPHS 64
#define CAP_SHIFT 6                   // 64 slots per node (deg = 1+Poisson(16))

#define CVTX_BLOCKS 5000              // N*128/4 float4s / 256
#define CVTW_BLOCKS 144               // 36864 / 256
#define CVT_BLOCKS (CVTX_BLOCKS + CVTW_BLOCKS)          // 5144
#define EBLOCKS ((E_TOT + 255) / 256)                   // 2660
#define GEMM_BLOCKS 625

typedef __attribute__((ext_vector_type(8))) short bf16x8;
typedef __attribute__((ext_vector_type(4))) float f32x4;

__device__ inline float bf2f(unsigned short u) {
    union { unsigned int i; float f; } v; v.i = ((unsigned int)u) << 16; return v.f;
}
__device__ inline unsigned short f2bf(float f) {
    union { float f; unsigned int i; } v; v.f = f;
    unsigned int r = v.i + 0x7FFF + ((v.i >> 16) & 1);
    return (unsigned short)(r >> 16);
}

// ---------------- cvt: x->bf16 + W transposes ----------------

__global__ __launch_bounds__(256) void cvt_kernel(const float* __restrict__ x,
                                                  const float* __restrict__ W0,
                                                  const float* __restrict__ W1,
                                                  const float* __restrict__ W2,
                                                  unsigned short* __restrict__ Xb,
                                                  unsigned short* __restrict__ Wt0,
                                                  unsigned short* __restrict__ Wt1,
                                                  unsigned short* __restrict__ Wt2) {
    int b = blockIdx.x;
    int tid = threadIdx.x;
    if (b < CVTX_BLOCKS) {
        int i = b * 256 + tid;
        float4 v = ((const float4*)x)[i];
        ushort4 o;
        o.x = f2bf(v.x); o.y = f2bf(v.y); o.z = f2bf(v.z); o.w = f2bf(v.w);
        ((ushort4*)Xb)[i] = o;
    } else {
        int idx = (b - CVTX_BLOCKS) * 256 + tid;
        if (idx < 16384) {
            int n = idx >> 7, k = idx & 127;
            Wt0[idx] = f2bf(W0[k * 128 + n]);
        } else if (idx < 32768) {
            int i = idx - 16384;
            int n = i >> 7, k = i & 127;
            Wt1[i] = f2bf(W1[k * 128 + n]);
        } else if (idx < 36864) {
            int i = idx - 32768;
            int n = i >> 7, k = i & 127;   // n in [0,32)
            Wt2[i] = f2bf(W2[k * 32 + n]);
        }
    }
}

// ---------------- gemm128 body (MFMA, bf16, fused attention scores) ----------------

__device__ __forceinline__ void gemm128_body(int blk,
                                             const unsigned short* __restrict__ Xb,
                                             const unsigned short* __restrict__ Wt,
                                             const float* __restrict__ asrc,
                                             const float* __restrict__ adst,
                                             unsigned short* __restrict__ Hb,
                                             float* __restrict__ ALS_t,
                                             float* __restrict__ ALD_t) {
    int wave = threadIdx.x >> 6;
    int lane = threadIdx.x & 63;
    int l15 = lane & 15;
    int q = lane >> 4;
    int r0 = (blk * 4 + wave) * 16;   // 625*4*16 = 40000 exact

    f32x4 acc[8];
#pragma unroll
    for (int t = 0; t < 8; ++t) acc[t] = (f32x4){0.f, 0.f, 0.f, 0.f};

    float asv[8], adv[8];
#pragma unroll
    for (int t = 0; t < 8; ++t) {
        int c = t * 16 + l15;
        asv[t] = asrc[c];
        adv[t] = adst[c];
    }

    const unsigned short* xrow = Xb + (long)(r0 + l15) * 128 + q * 8;
    const unsigned short* wrow = Wt + (long)l15 * 128 + q * 8;
#pragma unroll
    for (int kt = 0; kt < 4; ++kt) {
        bf16x8 a = *(const bf16x8*)(xrow + kt * 32);
#pragma unroll
        for (int t = 0; t < 8; ++t) {
            bf16x8 b = *(const bf16x8*)(wrow + (long)t * 16 * 128 + kt * 32);
            acc[t] = __builtin_amdgcn_mfma_f32_16x16x32_bf16(a, b, acc[t], 0, 0, 0);
        }
    }

#pragma unroll
    for (int t = 0; t < 8; ++t)
#pragma unroll
        for (int i = 0; i < 4; ++i)
            Hb[(long)(r0 + q * 4 + i) * 128 + t * 16 + l15] = f2bf(acc[t][i]);

#pragma unroll
    for (int i = 0; i < 4; ++i) {
        float ps0 = acc[0][i] * asv[0] + acc[1][i] * asv[1];
        float ps1 = acc[2][i] * asv[2] + acc[3][i] * asv[3];
        float ps2 = acc[4][i] * asv[4] + acc[5][i] * asv[5];
        float ps3 = acc[6][i] * asv[6] + acc[7][i] * asv[7];
        float pd0 = acc[0][i] * adv[0] + acc[1][i] * adv[1];
        float pd1 = acc[2][i] * adv[2] + acc[3][i] * adv[3];
        float pd2 = acc[4][i] * adv[4] + acc[5][i] * adv[5];
        float pd3 = acc[6][i] * adv[6] + acc[7][i] * adv[7];
#pragma unroll
        for (int m = 1; m < 16; m <<= 1) {
            ps0 += __shfl_xor(ps0, m, 16); ps1 += __shfl_xor(ps1, m, 16);
            ps2 += __shfl_xor(ps2, m, 16); ps3 += __shfl_xor(ps3, m, 16);
            pd0 += __shfl_xor(pd0, m, 16); pd1 += __shfl_xor(pd1, m, 16);
            pd2 += __shfl_xor(pd2, m, 16); pd3 += __shfl_xor(pd3, m, 16);
        }
        int r = r0 + q * 4 + i;
        if (l15 < 4) {
            float v = (l15 == 0) ? ps0 : (l15 == 1) ? ps1 : (l15 == 2) ? ps2 : ps3;
            ALS_t[l15 * N_NODES + r] = v;
        } else if (l15 < 8) {
            int h = l15 - 4;
            float v = (h == 0) ? pd0 : (h == 1) ? pd1 : (h == 2) ? pd2 : pd3;
            ALD_t[h * N_NODES + r] = v;
        }
    }
}

// ---------------- merged: gemm128 layer-0 || padded-bucket scatter (ushort ids) ----------------

__global__ __launch_bounds__(256) void gemm_scatter_kernel(const unsigned short* __restrict__ Xb,
                                                           const unsigned short* __restrict__ Wt,
                                                           const float* __restrict__ asrc,
                                                           const float* __restrict__ adst,
                                                           unsigned short* __restrict__ Hb,
                                                           float* __restrict__ ALS_t,
                                                           float* __restrict__ ALD_t,
                                                           const int* __restrict__ esrc,
                                                           const int* __restrict__ edst,
                                                           int* __restrict__ cnt,
                                                           unsigned short* __restrict__ psrc) {
    int b = blockIdx.x;
    if (b < GEMM_BLOCKS) {
        gemm128_body(b, Xb, Wt, asrc, adst, Hb, ALS_t, ALD_t);
    } else {
        int e = (b - GEMM_BLOCKS) * 256 + threadIdx.x;
        if (e < E_TOT) {
            int d, s;
            if (e < N_EDGES) { d = edst[e]; s = esrc[e]; }
            else             { d = e - N_EDGES; s = d; }
            int slot = atomicAdd(&cnt[d], 1);
            psrc[(d << CAP_SHIFT) + slot] = (unsigned short)s;
        }
    }
}

// standalone gemm128 for layer 1
__global__ __launch_bounds__(256) void gemm128_mfma(const unsigned short* __restrict__ Xb,
                                                    const unsigned short* __restrict__ Wt,
                                                    const float* __restrict__ asrc,
                                                    const float* __restrict__ adst,
                                                    unsigned short* __restrict__ Hb,
                                                    float* __restrict__ ALS_t,
                                                    float* __restrict__ ALD_t) {
    gemm128_body(blockIdx.x, Xb, Wt, asrc, adst, Hb, ALS_t, ALD_t);
}

// ---------------- MFMA GEMM (128 -> 32, 1 head) ----------------
__global__ __launch_bounds__(256) void gemm32_mfma(const unsigned short* __restrict__ Xb,
                                                   const unsigned short* __restrict__ Wt2,
                                                   const float* __restrict__ asrc,
                                                   const float* __restrict__ adst,
                                                   unsigned short* __restrict__ H2b,
                                                   float* __restrict__ ALS,
                                                   float* __restrict__ ALD) {
    int wave = threadIdx.x >> 6;
    int lane = threadIdx.x & 63;
    int l15 = lane & 15;
    int q = lane >> 4;
    int r0 = (blockIdx.x * 4 + wave) * 16;   // 625*4*16 = 40000 exact

    f32x4 acc[2];
    acc[0] = (f32x4){0.f, 0.f, 0.f, 0.f};
    acc[1] = (f32x4){0.f, 0.f, 0.f, 0.f};

    const unsigned short* xrow = Xb + (long)(r0 + l15) * 128 + q * 8;
    const unsigned short* wrow = Wt2 + (long)l15 * 128 + q * 8;
#pragma unroll
    for (int kt = 0; kt < 4; ++kt) {
        bf16x8 a = *(const bf16x8*)(xrow + kt * 32);
#pragma unroll
        for (int t = 0; t < 2; ++t) {
            bf16x8 b = *(const bf16x8*)(wrow + (long)t * 16 * 128 + kt * 32);
            acc[t] = __builtin_amdgcn_mfma_f32_16x16x32_bf16(a, b, acc[t], 0, 0, 0);
        }
    }

    float as0 = asrc[l15], as1 = asrc[16 + l15];
    float ad0 = adst[l15], ad1 = adst[16 + l15];
#pragma unroll
    for (int t = 0; t < 2; ++t)
#pragma unroll
        for (int i = 0; i < 4; ++i)
            H2b[(long)(r0 + q * 4 + i) * 32 + t * 16 + l15] = f2bf(acc[t][i]);

#pragma unroll
    for (int i = 0; i < 4; ++i) {
        float ps = acc[0][i] * as0 + acc[1][i] * as1;
        float pd = acc[0][i] * ad0 + acc[1][i] * ad1;
#pragma unroll
        for (int m = 1; m < 16; m <<= 1) {
            ps += __shfl_xor(ps, m, 16);
            pd += __shfl_xor(pd, m, 16);
        }
        if (l15 == 0) {
            int r = r0 + q * 4 + i;
            ALS[r] = ps;
            ALD[r] = pd;
        }
    }
}

// ---------------- Edge aggregation: wide-row gathers (2 rows / inst) ----------------
// One wave per node. Meta: lane (e16 = lane&15 edge slot, hh = lane>>4 head)
// computes w[edge][head] — 16 edges x 4 heads = 64 lanes, one value each.
// Consume: lane (half = lane>>5 edge parity, c4 = (lane&31)*4 channel block);
// round t gathers rows of edges {2t, 2t+1} in ONE 64-lane 8B-per-lane inst.
// Weight for channel block head hgrp=(lane&31)>>3 via bpermute shfl.
__global__ __launch_bounds__(256) void agg128(const unsigned short* __restrict__ Hb,
                                              const float* __restrict__ ALS_t,
                                              const float* __restrict__ ALD_t,
                                              const int* __restrict__ cnt,
                                              const unsigned short* __restrict__ psrc,
                                              const float* __restrict__ bias,
                                              unsigned short* __restrict__ OUTb) {
    int n = blockIdx.x * 4 + (threadIdx.x >> 6);
    n = __builtin_amdgcn_readfirstlane(n);
    if (n >= N_NODES) return;
    int lane = threadIdx.x & 63;
    int e16 = lane & 15;
    int hh = lane >> 4;           // meta head
    int half = lane >> 5;         // consume: edge parity
    int c4 = (lane & 31) * 4;     // consume: channel base (4 ch)
    int hgrp = (lane & 31) >> 3;  // head of my channel block
    float aldh = ALD_t[hh * N_NODES + n];
    const float* alsh = ALS_t + (long)hh * N_NODES;
    int j0 = n << CAP_SHIFT;
    int j1 = j0 + __builtin_amdgcn_readfirstlane(cnt[n]);
    float a0 = 0.f, a1 = 0.f, a2 = 0.f, a3 = 0.f, dsum = 0.f;
    int wsrc = hgrp * 16 + half;  // + 2t
    for (int jb = j0; jb < j1; jb += 16) {
        int j = jb + e16;
        int jc = (j < j1) ? j : (j1 - 1);
        int s = psrc[jc];
        float e = alsh[s] + aldh;
        e = (e > 0.f) ? e : 0.2f * e;
        float w = (j < j1) ? __expf(e) : 0.f;
        dsum += w;
#pragma unroll
        for (int t = 0; t < 8; ++t) {
            int se = __shfl(s, t * 2 + half, 16);
            uint2 hv = *(const uint2*)(Hb + (long)se * 128 + c4);
            float wv = __shfl(w, wsrc + t * 2);
            a0 += wv * bf2f((unsigned short)(hv.x & 0xFFFF));
            a1 += wv * bf2f((unsigned short)(hv.x >> 16));
            a2 += wv * bf2f((unsigned short)(hv.y & 0xFFFF));
            a3 += wv * bf2f((unsigned short)(hv.y >> 16));
        }
    }
    // acc: halves hold disjoint edges of same channel block
    a0 += __shfl_xor(a0, 32); a1 += __shfl_xor(a1, 32);
    a2 += __shfl_xor(a2, 32); a3 += __shfl_xor(a3, 32);
    // dsum: reduce within each head group, then fetch my channel head's total
#pragma unroll
    for (int m = 1; m < 16; m <<= 1) dsum += __shfl_xor(dsum, m, 16);
    float dsv = __shfl(dsum, hgrp * 16);
    if (half == 0) {
        float inv = 1.0f / dsv;
        float4 bv = *(const float4*)(bias + c4);
        float o0 = a0 * inv + bv.x;
        float o1 = a1 * inv + bv.y;
        float o2 = a2 * inv + bv.z;
        float o3 = a3 * inv + bv.w;
        o0 = (o0 > 0.f) ? o0 : (__expf(o0) - 1.f);
        o1 = (o1 > 0.f) ? o1 : (__expf(o1) - 1.f);
        o2 = (o2 > 0.f) ? o2 : (__expf(o2) - 1.f);
        o3 = (o3 > 0.f) ? o3 : (__expf(o3) - 1.f);
        ushort4 ov;
        ov.x = f2bf(o0); ov.y = f2bf(o1); ov.z = f2bf(o2); ov.w = f2bf(o3);
        *(ushort4*)(OUTb + (long)n * 128 + c4) = ov;
    }
}

// 32-channel, 1-head; half-wave per node, padded buckets (ushort ids).
__global__ __launch_bounds__(256) void agg32(const unsigned short* __restrict__ H2b,
                                             const float* __restrict__ ALS,
                                             const float* __restrict__ ALD,
                                             const int* __restrict__ cnt,
                                             const unsigned short* __restrict__ psrc,
                                             const float* __restrict__ bias,
                                             float* __restrict__ OUT) {
    int wv = blockIdx.x * 4 + (threadIdx.x >> 6);
    int lane = threadIdx.x & 63;
    int col = lane & 31;
    int half = lane >> 5;
    int e16 = lane & 15;
    int n = wv * 2 + half;
    if (n >= N_NODES) return;
    float aldn = ALD[n];
    int j0 = n << CAP_SHIFT;
    int j1 = j0 + cnt[n];
    float a = 0.f, dsum = 0.f;
    for (int jb = j0; jb < j1; jb += 16) {
        int j = jb + e16;
        int jc = (j < j1) ? j : (j1 - 1);
        int s = psrc[jc];
        float e = ALS[s] + aldn;
        e = (e > 0.f) ? e : 0.2f * e;
        float w = (j < j1) ? __expf(e) : 0.f;
        int st[16]; float wt[16];
#pragma unroll
        for (int t = 0; t < 16; ++t) {
            st[t] = __shfl(s, t, 16);
            wt[t] = __shfl(w, t, 16);
        }
        unsigned short hv[16];
#pragma unroll
        for (int t = 0; t < 16; ++t)
            hv[t] = H2b[st[t] * 32 + col];
#pragma unroll
        for (int t = 0; t < 16; ++t) {
            dsum += wt[t];
            a += wt[t] * bf2f(hv[t]);
        }
    }
    float o = a / dsum + bias[col];
    o = (o > 0.f) ? o : (__expf(o) - 1.f);
    OUT[n * 32 + col] = o;
}

// ---------------- Pooling + MLP ----------------
__global__ __launch_bounds__(256) void pool_kernel(const float* __restrict__ H3,
                                                   const int* __restrict__ batch,
                                                   float* __restrict__ gsum,
                                                   float* __restrict__ gcnt) {
    const int CHUNK = 40;
    int gid = (blockIdx.x * 256 + threadIdx.x) >> 5;
    int c = threadIdx.x & 31;
    int n0 = gid * CHUNK;
    if (n0 >= N_NODES) return;
    int n1 = n0 + CHUNK;
    if (n1 > N_NODES) n1 = N_NODES;
    int cur = batch[n0];
    float acc = 0.f;
    int cnt = 0;
    for (int n = n0; n < n1; ++n) {
        int b = batch[n];
        if (b != cur) {
            atomicAdd(&gsum[cur * 32 + c], acc);
            if (c == 0) atomicAdd(&gcnt[cur], (float)cnt);
            cur = b; acc = 0.f; cnt = 0;
        }
        acc += H3[n * 32 + c];
        cnt++;
    }
    atomicAdd(&gsum[cur * 32 + c], acc);
    if (c == 0) atomicAdd(&gcnt[cur], (float)cnt);
}

__global__ __launch_bounds__(256) void mlp_kernel(const float* __restrict__ gsum,
                                                  const float* __restrict__ gcnt,
                                                  const float* __restrict__ l1w,
                                                  const float* __restrict__ l1b,
                                                  const float* __restrict__ l2w,
                                                  const float* __restrict__ l2b,
                                                  float* __restrict__ out) {
    __shared__ float g[NUM_GRAPHS * 32];
    __shared__ float t1[NUM_GRAPHS * 128];
    int tid = threadIdx.x;
    for (int i = tid; i < NUM_GRAPHS * 32; i += 256) {
        float c = gcnt[i >> 5];
        g[i] = gsum[i] / fmaxf(c, 1.0f);
    }
    __syncthreads();
    for (int i = tid; i < NUM_GRAPHS * 128; i += 256) {
        int r = i >> 7, j = i & 127;
        float a = l1b[j];
        for (int k = 0; k < 32; ++k) a += g[r * 32 + k] * l1w[k * 128 + j];
        t1[i] = fmaxf(a, 0.f);
    }
    __syncthreads();
    for (int i = tid; i < NUM_GRAPHS * 8; i += 256) {
        int r = i >> 3, j = i & 7;
        float a = l2b[j];
        for (int k = 0; k < 128; ++k) a += t1[r * 128 + k] * l2w[k * 8 + j];
        out[i] = a;
    }
}

// ---------------- host ----------------

extern "C" void kernel_launch(void* const* d_in, const int* in_sizes, int n_in,
                              void* d_out, int out_size, void* d_ws, size_t ws_size,
                              hipStream_t stream) {
    const float* x      = (const float*)d_in[0];
    const int*   eidx   = (const int*)d_in[1];
    const int*   batch  = (const int*)d_in[2];
    const float* W0     = (const float*)d_in[3];
    const float* asrc0  = (const float*)d_in[4];
    const float* adst0  = (const float*)d_in[5];
    const float* b0     = (const float*)d_in[6];
    const float* W1     = (const float*)d_in[7];
    const float* asrc1  = (const float*)d_in[8];
    const float* adst1  = (const float*)d_in[9];
    const float* b1     = (const float*)d_in[10];
    const float* W2     = (const float*)d_in[11];
    const float* asrc2  = (const float*)d_in[12];
    const float* adst2  = (const float*)d_in[13];
    const float* b2     = (const float*)d_in[14];
    const float* l1w    = (const float*)d_in[15];
    const float* l1b    = (const float*)d_in[16];
    const float* l2w    = (const float*)d_in[17];
    const float* l2b    = (const float*)d_in[18];
    float* out = (float*)d_out;

    const int* esrc = eidx;
    const int* edst = eidx + N_EDGES;

    // workspace layout
    float* ALS  = (float*)d_ws;                       // N*4 (transposed [4][N]; layer2 uses [N])
    float* ALD  = ALS + N_NODES * 4;                  // N*4
    float* h3   = ALD + N_NODES * 4;                  // N*32
    int* cnt    = (int*)(h3 + (long)N_NODES * 32);    // N      <- zero from here
    float* gsum = (float*)(cnt + N_NODES);            // 64*32
    float* gcnt = gsum + NUM_GRAPHS * 32;             // 64     <- zero to here
    unsigned short* psrc = (unsigned short*)(gcnt + NUM_GRAPHS);  // N*64 ushort (5.12 MB)
    uintptr_t p = (uintptr_t)(psrc + ((long)N_NODES << CAP_SHIFT));
    p = (p + 15) & ~(uintptr_t)15;
    unsigned short* Xb   = (unsigned short*)p;              // N*128 bf16
    unsigned short* Hb   = Xb + (long)N_NODES * 128;        // N*128 bf16
    unsigned short* OUTb = Hb + (long)N_NODES * 128;        // N*128 bf16
    unsigned short* H2b  = OUTb + (long)N_NODES * 128;      // N*32 bf16
    unsigned short* Wt0  = H2b + (long)N_NODES * 32;        // 128*128 bf16
    unsigned short* Wt1  = Wt0 + 128 * 128;                 // 128*128 bf16
    unsigned short* Wt2  = Wt1 + 128 * 128;                 // 32*128 bf16

    // zero cnt/gsum/gcnt (contiguous)
    size_t zbytes = (size_t)(N_NODES + NUM_GRAPHS * 32 + NUM_GRAPHS) * 4;
    hipMemsetAsync(cnt, 0, zbytes, stream);

    // conversions
    cvt_kernel<<<CVT_BLOCKS, 256, 0, stream>>>(x, W0, W1, W2, Xb, Wt0, Wt1, Wt2);

    // merged: gemm128 layer-0 || padded-bucket scatter (single atomic pass)
    gemm_scatter_kernel<<<GEMM_BLOCKS + EBLOCKS, 256, 0, stream>>>(
        Xb, Wt0, asrc0, adst0, Hb, ALS, ALD, esrc, edst, cnt, psrc);
    agg128<<<10000, 256, 0, stream>>>(Hb, ALS, ALD, cnt, psrc, b0, OUTb);

    // layer 1
    gemm128_mfma<<<GEMM_BLOCKS, 256, 0, stream>>>(OUTb, Wt1, asrc1, adst1, Hb, ALS, ALD);
    agg128<<<10000, 256, 0, stream>>>(Hb, ALS, ALD, cnt, psrc, b1, OUTb);

    // layer 2
    gemm32_mfma<<<GEMM_BLOCKS, 256, 0, stream>>>(OUTb, Wt2, asrc2, adst2, H2b, ALS, ALD);
    agg32<<<5000, 256, 0, stream>>>(H2b, ALS, ALD, cnt, psrc, b2, h3);

    // pool + MLP
    pool_kernel<<<125, 256, 0, stream>>>(h3, batch, gsum, gcnt);
    mlp_kernel<<<1, 256, 0, stream>>>(gsum, gcnt, l1w, l1b, l2w, l2b, out);
}

// Round 16
// 289.463 us; speedup vs baseline: 1.0336x; 1.0336x over previous
//
#include <hip/hip_runtime.h>
#include <hip/hip_bf16.h>

#define N_NODES 40000
#define N_EDGES 640000
#define E_TOT   (N_EDGES + N_NODES)
#define NUM_GRAPHS 64
#define CAP_SHIFT 6                   // 64 slots per node (deg = 1+Poisson(16))

#define CVTX_BLOCKS 5000              // N*128/4 float4s / 256
#define CVTW_BLOCKS 144               // 36864 / 256
#define CVT_BLOCKS (CVTX_BLOCKS + CVTW_BLOCKS)          // 5144
#define EBLOCKS ((E_TOT + 255) / 256)                   // 2660
#define GEMM_BLOCKS 625

typedef __attribute__((ext_vector_type(8))) short bf16x8;
typedef __attribute__((ext_vector_type(4))) float f32x4;

__device__ inline float bf2f(unsigned short u) {
    union { unsigned int i; float f; } v; v.i = ((unsigned int)u) << 16; return v.f;
}
__device__ inline unsigned short f2bf(float f) {
    union { float f; unsigned int i; } v; v.f = f;
    unsigned int r = v.i + 0x7FFF + ((v.i >> 16) & 1);
    return (unsigned short)(r >> 16);
}

// ---------------- cvt: x->bf16 + W transposes ----------------

__global__ __launch_bounds__(256) void cvt_kernel(const float* __restrict__ x,
                                                  const float* __restrict__ W0,
                                                  const float* __restrict__ W1,
                                                  const float* __restrict__ W2,
                                                  unsigned short* __restrict__ Xb,
                                                  unsigned short* __restrict__ Wt0,
                                                  unsigned short* __restrict__ Wt1,
                                                  unsigned short* __restrict__ Wt2) {
    int b = blockIdx.x;
    int tid = threadIdx.x;
    if (b < CVTX_BLOCKS) {
        int i = b * 256 + tid;
        float4 v = ((const float4*)x)[i];
        ushort4 o;
        o.x = f2bf(v.x); o.y = f2bf(v.y); o.z = f2bf(v.z); o.w = f2bf(v.w);
        ((ushort4*)Xb)[i] = o;
    } else {
        int idx = (b - CVTX_BLOCKS) * 256 + tid;
        if (idx < 16384) {
            int n = idx >> 7, k = idx & 127;
            Wt0[idx] = f2bf(W0[k * 128 + n]);
        } else if (idx < 32768) {
            int i = idx - 16384;
            int n = i >> 7, k = i & 127;
            Wt1[i] = f2bf(W1[k * 128 + n]);
        } else if (idx < 36864) {
            int i = idx - 32768;
            int n = i >> 7, k = i & 127;   // n in [0,32)
            Wt2[i] = f2bf(W2[k * 32 + n]);
        }
    }
}

// ---------------- gemm128 body (MFMA, bf16, fused attention scores) ----------------

__device__ __forceinline__ void gemm128_body(int blk,
                                             const unsigned short* __restrict__ Xb,
                                             const unsigned short* __restrict__ Wt,
                                             const float* __restrict__ asrc,
                                             const float* __restrict__ adst,
                                             unsigned short* __restrict__ Hb,
                                             float* __restrict__ ALS_t,
                                             float* __restrict__ ALD_t) {
    int wave = threadIdx.x >> 6;
    int lane = threadIdx.x & 63;
    int l15 = lane & 15;
    int q = lane >> 4;
    int r0 = (blk * 4 + wave) * 16;   // 625*4*16 = 40000 exact

    f32x4 acc[8];
#pragma unroll
    for (int t = 0; t < 8; ++t) acc[t] = (f32x4){0.f, 0.f, 0.f, 0.f};

    float asv[8], adv[8];
#pragma unroll
    for (int t = 0; t < 8; ++t) {
        int c = t * 16 + l15;
        asv[t] = asrc[c];
        adv[t] = adst[c];
    }

    const unsigned short* xrow = Xb + (long)(r0 + l15) * 128 + q * 8;
    const unsigned short* wrow = Wt + (long)l15 * 128 + q * 8;
#pragma unroll
    for (int kt = 0; kt < 4; ++kt) {
        bf16x8 a = *(const bf16x8*)(xrow + kt * 32);
#pragma unroll
        for (int t = 0; t < 8; ++t) {
            bf16x8 b = *(const bf16x8*)(wrow + (long)t * 16 * 128 + kt * 32);
            acc[t] = __builtin_amdgcn_mfma_f32_16x16x32_bf16(a, b, acc[t], 0, 0, 0);
        }
    }

#pragma unroll
    for (int t = 0; t < 8; ++t)
#pragma unroll
        for (int i = 0; i < 4; ++i)
            Hb[(long)(r0 + q * 4 + i) * 128 + t * 16 + l15] = f2bf(acc[t][i]);

#pragma unroll
    for (int i = 0; i < 4; ++i) {
        float ps0 = acc[0][i] * asv[0] + acc[1][i] * asv[1];
        float ps1 = acc[2][i] * asv[2] + acc[3][i] * asv[3];
        float ps2 = acc[4][i] * asv[4] + acc[5][i] * asv[5];
        float ps3 = acc[6][i] * asv[6] + acc[7][i] * asv[7];
        float pd0 = acc[0][i] * adv[0] + acc[1][i] * adv[1];
        float pd1 = acc[2][i] * adv[2] + acc[3][i] * adv[3];
        float pd2 = acc[4][i] * adv[4] + acc[5][i] * adv[5];
        float pd3 = acc[6][i] * adv[6] + acc[7][i] * adv[7];
#pragma unroll
        for (int m = 1; m < 16; m <<= 1) {
            ps0 += __shfl_xor(ps0, m, 16); ps1 += __shfl_xor(ps1, m, 16);
            ps2 += __shfl_xor(ps2, m, 16); ps3 += __shfl_xor(ps3, m, 16);
            pd0 += __shfl_xor(pd0, m, 16); pd1 += __shfl_xor(pd1, m, 16);
            pd2 += __shfl_xor(pd2, m, 16); pd3 += __shfl_xor(pd3, m, 16);
        }
        int r = r0 + q * 4 + i;
        if (l15 < 4) {
            float v = (l15 == 0) ? ps0 : (l15 == 1) ? ps1 : (l15 == 2) ? ps2 : ps3;
            ALS_t[l15 * N_NODES + r] = v;
        } else if (l15 < 8) {
            int h = l15 - 4;
            float v = (h == 0) ? pd0 : (h == 1) ? pd1 : (h == 2) ? pd2 : pd3;
            ALD_t[h * N_NODES + r] = v;
        }
    }
}

// ---------------- merged: gemm128 layer-0 || padded-bucket scatter ----------------
// Single atomic pass builds the bucketed adjacency: slot = atomicAdd(cnt[d]),
// psrc[d*64+slot] = s. No hist, no scans. Disjoint outputs vs gemm.

__global__ __launch_bounds__(256) void gemm_scatter_kernel(const unsigned short* __restrict__ Xb,
                                                           const unsigned short* __restrict__ Wt,
                                                           const float* __restrict__ asrc,
                                                           const float* __restrict__ adst,
                                                           unsigned short* __restrict__ Hb,
                                                           float* __restrict__ ALS_t,
                                                           float* __restrict__ ALD_t,
                                                           const int* __restrict__ esrc,
                                                           const int* __restrict__ edst,
                                                           int* __restrict__ cnt,
                                                           int* __restrict__ psrc) {
    int b = blockIdx.x;
    if (b < GEMM_BLOCKS) {
        gemm128_body(b, Xb, Wt, asrc, adst, Hb, ALS_t, ALD_t);
    } else {
        int e = (b - GEMM_BLOCKS) * 256 + threadIdx.x;
        if (e < E_TOT) {
            int d, s;
            if (e < N_EDGES) { d = edst[e]; s = esrc[e]; }
            else             { d = e - N_EDGES; s = d; }
            int slot = atomicAdd(&cnt[d], 1);
            psrc[(d << CAP_SHIFT) + slot] = s;
        }
    }
}

// standalone gemm128 for layer 1
__global__ __launch_bounds__(256) void gemm128_mfma(const unsigned short* __restrict__ Xb,
                                                    const unsigned short* __restrict__ Wt,
                                                    const float* __restrict__ asrc,
                                                    const float* __restrict__ adst,
                                                    unsigned short* __restrict__ Hb,
                                                    float* __restrict__ ALS_t,
                                                    float* __restrict__ ALD_t) {
    gemm128_body(blockIdx.x, Xb, Wt, asrc, adst, Hb, ALS_t, ALD_t);
}

// ---------------- MFMA GEMM (128 -> 32, 1 head) ----------------
__global__ __launch_bounds__(256) void gemm32_mfma(const unsigned short* __restrict__ Xb,
                                                   const unsigned short* __restrict__ Wt2,
                                                   const float* __restrict__ asrc,
                                                   const float* __restrict__ adst,
                                                   unsigned short* __restrict__ H2b,
                                                   float* __restrict__ ALS,
                                                   float* __restrict__ ALD) {
    int wave = threadIdx.x >> 6;
    int lane = threadIdx.x & 63;
    int l15 = lane & 15;
    int q = lane >> 4;
    int r0 = (blockIdx.x * 4 + wave) * 16;   // 625*4*16 = 40000 exact

    f32x4 acc[2];
    acc[0] = (f32x4){0.f, 0.f, 0.f, 0.f};
    acc[1] = (f32x4){0.f, 0.f, 0.f, 0.f};

    const unsigned short* xrow = Xb + (long)(r0 + l15) * 128 + q * 8;
    const unsigned short* wrow = Wt2 + (long)l15 * 128 + q * 8;
#pragma unroll
    for (int kt = 0; kt < 4; ++kt) {
        bf16x8 a = *(const bf16x8*)(xrow + kt * 32);
#pragma unroll
        for (int t = 0; t < 2; ++t) {
            bf16x8 b = *(const bf16x8*)(wrow + (long)t * 16 * 128 + kt * 32);
            acc[t] = __builtin_amdgcn_mfma_f32_16x16x32_bf16(a, b, acc[t], 0, 0, 0);
        }
    }

    float as0 = asrc[l15], as1 = asrc[16 + l15];
    float ad0 = adst[l15], ad1 = adst[16 + l15];
#pragma unroll
    for (int t = 0; t < 2; ++t)
#pragma unroll
        for (int i = 0; i < 4; ++i)
            H2b[(long)(r0 + q * 4 + i) * 32 + t * 16 + l15] = f2bf(acc[t][i]);

#pragma unroll
    for (int i = 0; i < 4; ++i) {
        float ps = acc[0][i] * as0 + acc[1][i] * as1;
        float pd = acc[0][i] * ad0 + acc[1][i] * ad1;
#pragma unroll
        for (int m = 1; m < 16; m <<= 1) {
            ps += __shfl_xor(ps, m, 16);
            pd += __shfl_xor(pd, m, 16);
        }
        if (l15 == 0) {
            int r = r0 + q * 4 + i;
            ALS[r] = ps;
            ALD[r] = pd;
        }
    }
}

// ---------------- Edge aggregation (padded buckets, R8/R13 form) ----------------
__global__ __launch_bounds__(256) void agg128(const unsigned short* __restrict__ Hb,
                                              const float* __restrict__ ALS_t,
                                              const float* __restrict__ ALD_t,
                                              const int* __restrict__ cnt,
                                              const int* __restrict__ psrc,
                                              const float* __restrict__ bias,
                                              unsigned short* __restrict__ OUTb) {
    int n = blockIdx.x * 4 + (threadIdx.x >> 6);
    n = __builtin_amdgcn_readfirstlane(n);
    if (n >= N_NODES) return;
    int lane = threadIdx.x & 63;
    int c = lane * 2;
    int head = lane >> 4;
    int e16 = lane & 15;
    float aldh = ALD_t[head * N_NODES + n];
    const float* alsh = ALS_t + (long)head * N_NODES;
    int j0 = n << CAP_SHIFT;
    int j1 = j0 + __builtin_amdgcn_readfirstlane(cnt[n]);
    float a0 = 0.f, a1 = 0.f, dsum = 0.f;
    for (int jb = j0; jb < j1; jb += 16) {
        int j = jb + e16;
        int jc = (j < j1) ? j : (j1 - 1);
        int s = psrc[jc];
        float e = alsh[s] + aldh;
        e = (e > 0.f) ? e : 0.2f * e;
        float w = (j < j1) ? __expf(e) : 0.f;
        int st[16]; float wt[16];
#pragma unroll
        for (int t = 0; t < 16; ++t) {
            st[t] = __shfl(s, t, 16);
            wt[t] = __shfl(w, t, 16);
        }
        unsigned int hv[16];
#pragma unroll
        for (int t = 0; t < 16; ++t)
            hv[t] = *(const unsigned int*)(Hb + (long)st[t] * 128 + c);
#pragma unroll
        for (int t = 0; t < 16; ++t) {
            float h0 = bf2f((unsigned short)(hv[t] & 0xFFFF));
            float h1 = bf2f((unsigned short)(hv[t] >> 16));
            dsum += wt[t];
            a0 += wt[t] * h0;
            a1 += wt[t] * h1;
        }
    }
    float inv = 1.0f / dsum;
    float o0 = a0 * inv + bias[c];
    float o1 = a1 * inv + bias[c + 1];
    o0 = (o0 > 0.f) ? o0 : (__expf(o0) - 1.f);
    o1 = (o1 > 0.f) ? o1 : (__expf(o1) - 1.f);
    ushort2 ob; ob.x = f2bf(o0); ob.y = f2bf(o1);
    *(ushort2*)(OUTb + (long)n * 128 + c) = ob;
}

// 32-channel, 1-head; half-wave per node, padded buckets.
__global__ __launch_bounds__(256) void agg32(const unsigned short* __restrict__ H2b,
                                             const float* __restrict__ ALS,
                                             const float* __restrict__ ALD,
                                             const int* __restrict__ cnt,
                                             const int* __restrict__ psrc,
                                             const float* __restrict__ bias,
                                             float* __restrict__ OUT) {
    int wv = blockIdx.x * 4 + (threadIdx.x >> 6);
    int lane = threadIdx.x & 63;
    int col = lane & 31;
    int half = lane >> 5;
    int e16 = lane & 15;
    int n = wv * 2 + half;
    if (n >= N_NODES) return;
    float aldn = ALD[n];
    int j0 = n << CAP_SHIFT;
    int j1 = j0 + cnt[n];
    float a = 0.f, dsum = 0.f;
    for (int jb = j0; jb < j1; jb += 16) {
        int j = jb + e16;
        int jc = (j < j1) ? j : (j1 - 1);
        int s = psrc[jc];
        float e = ALS[s] + aldn;
        e = (e > 0.f) ? e : 0.2f * e;
        float w = (j < j1) ? __expf(e) : 0.f;
        int st[16]; float wt[16];
#pragma unroll
        for (int t = 0; t < 16; ++t) {
            st[t] = __shfl(s, t, 16);
            wt[t] = __shfl(w, t, 16);
        }
        unsigned short hv[16];
#pragma unroll
        for (int t = 0; t < 16; ++t)
            hv[t] = H2b[st[t] * 32 + col];
#pragma unroll
        for (int t = 0; t < 16; ++t) {
            dsum += wt[t];
            a += wt[t] * bf2f(hv[t]);
        }
    }
    float o = a / dsum + bias[col];
    o = (o > 0.f) ? o : (__expf(o) - 1.f);
    OUT[n * 32 + col] = o;
}

// ---------------- Pooling + MLP ----------------
__global__ __launch_bounds__(256) void pool_kernel(const float* __restrict__ H3,
                                                   const int* __restrict__ batch,
                                                   float* __restrict__ gsum,
                                                   float* __restrict__ gcnt) {
    const int CHUNK = 40;
    int gid = (blockIdx.x * 256 + threadIdx.x) >> 5;
    int c = threadIdx.x & 31;
    int n0 = gid * CHUNK;
    if (n0 >= N_NODES) return;
    int n1 = n0 + CHUNK;
    if (n1 > N_NODES) n1 = N_NODES;
    int cur = batch[n0];
    float acc = 0.f;
    int cnt = 0;
    for (int n = n0; n < n1; ++n) {
        int b = batch[n];
        if (b != cur) {
            atomicAdd(&gsum[cur * 32 + c], acc);
            if (c == 0) atomicAdd(&gcnt[cur], (float)cnt);
            cur = b; acc = 0.f; cnt = 0;
        }
        acc += H3[n * 32 + c];
        cnt++;
    }
    atomicAdd(&gsum[cur * 32 + c], acc);
    if (c == 0) atomicAdd(&gcnt[cur], (float)cnt);
}

__global__ __launch_bounds__(256) void mlp_kernel(const float* __restrict__ gsum,
                                                  const float* __restrict__ gcnt,
                                                  const float* __restrict__ l1w,
                                                  const float* __restrict__ l1b,
                                                  const float* __restrict__ l2w,
                                                  const float* __restrict__ l2b,
                                                  float* __restrict__ out) {
    __shared__ float g[NUM_GRAPHS * 32];
    __shared__ float t1[NUM_GRAPHS * 128];
    int tid = threadIdx.x;
    for (int i = tid; i < NUM_GRAPHS * 32; i += 256) {
        float c = gcnt[i >> 5];
        g[i] = gsum[i] / fmaxf(c, 1.0f);
    }
    __syncthreads();
    for (int i = tid; i < NUM_GRAPHS * 128; i += 256) {
        int r = i >> 7, j = i & 127;
        float a = l1b[j];
        for (int k = 0; k < 32; ++k) a += g[r * 32 + k] * l1w[k * 128 + j];
        t1[i] = fmaxf(a, 0.f);
    }
    __syncthreads();
    for (int i = tid; i < NUM_GRAPHS * 8; i += 256) {
        int r = i >> 3, j = i & 7;
        float a = l2b[j];
        for (int k = 0; k < 128; ++k) a += t1[r * 128 + k] * l2w[k * 8 + j];
        out[i] = a;
    }
}

// ---------------- host ----------------

extern "C" void kernel_launch(void* const* d_in, const int* in_sizes, int n_in,
                              void* d_out, int out_size, void* d_ws, size_t ws_size,
                              hipStream_t stream) {
    const float* x      = (const float*)d_in[0];
    const int*   eidx   = (const int*)d_in[1];
    const int*   batch  = (const int*)d_in[2];
    const float* W0     = (const float*)d_in[3];
    const float* asrc0  = (const float*)d_in[4];
    const float* adst0  = (const float*)d_in[5];
    const float* b0     = (const float*)d_in[6];
    const float* W1     = (const float*)d_in[7];
    const float* asrc1  = (const float*)d_in[8];
    const float* adst1  = (const float*)d_in[9];
    const float* b1     = (const float*)d_in[10];
    const float* W2     = (const float*)d_in[11];
    const float* asrc2  = (const float*)d_in[12];
    const float* adst2  = (const float*)d_in[13];
    const float* b2     = (const float*)d_in[14];
    const float* l1w    = (const float*)d_in[15];
    const float* l1b    = (const float*)d_in[16];
    const float* l2w    = (const float*)d_in[17];
    const float* l2b    = (const float*)d_in[18];
    float* out = (float*)d_out;

    const int* esrc = eidx;
    const int* edst = eidx + N_EDGES;

    // workspace layout
    float* ALS  = (float*)d_ws;                       // N*4 (transposed [4][N]; layer2 uses [N])
    float* ALD  = ALS + N_NODES * 4;                  // N*4
    float* h3   = ALD + N_NODES * 4;                  // N*32
    int* cnt    = (int*)(h3 + (long)N_NODES * 32);    // N      <- zero from here
    float* gsum = (float*)(cnt + N_NODES);            // 64*32
    float* gcnt = gsum + NUM_GRAPHS * 32;             // 64     <- zero to here
    int* psrc   = (int*)(gcnt + NUM_GRAPHS);          // N*64 padded buckets (10.24 MB)
    uintptr_t p = (uintptr_t)(psrc + ((long)N_NODES << CAP_SHIFT));
    p = (p + 15) & ~(uintptr_t)15;
    unsigned short* Xb   = (unsigned short*)p;              // N*128 bf16
    unsigned short* Hb   = Xb + (long)N_NODES * 128;        // N*128 bf16
    unsigned short* OUTb = Hb + (long)N_NODES * 128;        // N*128 bf16
    unsigned short* H2b  = OUTb + (long)N_NODES * 128;      // N*32 bf16
    unsigned short* Wt0  = H2b + (long)N_NODES * 32;        // 128*128 bf16
    unsigned short* Wt1  = Wt0 + 128 * 128;                 // 128*128 bf16
    unsigned short* Wt2  = Wt1 + 128 * 128;                 // 32*128 bf16

    // zero cnt/gsum/gcnt (contiguous)
    size_t zbytes = (size_t)(N_NODES + NUM_GRAPHS * 32 + NUM_GRAPHS) * 4;
    hipMemsetAsync(cnt, 0, zbytes, stream);

    // conversions
    cvt_kernel<<<CVT_BLOCKS, 256, 0, stream>>>(x, W0, W1, W2, Xb, Wt0, Wt1, Wt2);

    // merged: gemm128 layer-0 || padded-bucket scatter (single atomic pass)
    gemm_scatter_kernel<<<GEMM_BLOCKS + EBLOCKS, 256, 0, stream>>>(
        Xb, Wt0, asrc0, adst0, Hb, ALS, ALD, esrc, edst, cnt, psrc);
    agg128<<<10000, 256, 0, stream>>>(Hb, ALS, ALD, cnt, psrc, b0, OUTb);

    // layer 1
    gemm128_mfma<<<GEMM_BLOCKS, 256, 0, stream>>>(OUTb, Wt1, asrc1, adst1, Hb, ALS, ALD);
    agg128<<<10000, 256, 0, stream>>>(Hb, ALS, ALD, cnt, psrc, b1, OUTb);

    // layer 2
    gemm32_mfma<<<GEMM_BLOCKS, 256, 0, stream>>>(OUTb, Wt2, asrc2, adst2, H2b, ALS, ALD);
    agg32<<<5000, 256, 0, stream>>>(H2b, ALS, ALD, cnt, psrc, b2, h3);

    // pool + MLP
    pool_kernel<<<125, 256, 0, stream>>>(h3, batch, gsum, gcnt);
    mlp_kernel<<<1, 256, 0, stream>>>(gsum, gcnt, l1w, l1b, l2w, l2b, out);
}